// Round 8
// baseline (679.605 us; speedup 1.0000x reference)
//
#include <hip/hip_runtime.h>
#include <stdint.h>

#define DEV __device__ __forceinline__

typedef __attribute__((ext_vector_type(8))) short bh8;
typedef __attribute__((ext_vector_type(4))) float f4;
#define LDS_AS __attribute__((address_space(3)))
#define GLB_AS __attribute__((address_space(1)))

DEV unsigned short f2bf(float f) {
    union { float f; uint32_t u; } c; c.f = f;
    uint32_t u = c.u;
    uint32_t r = (u + 0x7fffu + ((u >> 16) & 1u)) >> 16;
    return (unsigned short)r;
}
DEV float bf2f(unsigned short h) {
    union { uint32_t u; float f; } c; c.u = ((uint32_t)h) << 16;
    return c.f;
}

// fp8 e4m3 (non-negative only), stored value = v * 256 (v in [0, ~1]).
DEV uint8_t f2fp8(float v) {
    const float vs = v * 256.f;
    union { float f; uint32_t u; } c; c.f = vs;
    const uint32_t u = c.u + 0x7ffffu + ((c.u >> 20) & 1u);
    const uint32_t f8 = (u >> 20) - 960u;            // ((e8-120)<<3)|m3
    return (vs < 0.015625f) ? (uint8_t)0 : (uint8_t)f8;
}
DEV float fp8w(uint32_t x) { union { uint32_t u; float f; } c; c.u = x; return c.f; }

DEV void gload16(const void* g, void* l) {
    __builtin_amdgcn_global_load_lds((const GLB_AS uint32_t*)g, (LDS_AS uint32_t*)l, 16, 0, 0);
}

// ---------------- prep: x-cvt + 6 weight-cvts + rowptr, one launch ----------------
__global__ __launch_bounds__(256) void prep_kernel(
    const float* __restrict__ x, unsigned short* __restrict__ xb, int n4x, int nbx,
    const float* __restrict__ w0, const float* __restrict__ w1, const float* __restrict__ w2,
    const float* __restrict__ w3, const float* __restrict__ w4, const float* __restrict__ w5,
    unsigned short* __restrict__ wbBase,
    const int* __restrict__ dst, int* __restrict__ rp, int N, int E) {
    const int b = blockIdx.x;
    if (b < nbx) {
        const int i = b * 256 + threadIdx.x;
        if (i < n4x) {
            const float4 v = ((const float4*)x)[i];
            ushort4 o; o.x = f2bf(v.x); o.y = f2bf(v.y); o.z = f2bf(v.z); o.w = f2bf(v.w);
            ((ushort4*)xb)[i] = o;
        }
    } else if (b < nbx + 384) {
        const int wi = (b - nbx) >> 6;
        const int i = ((b - nbx) & 63) * 256 + threadIdx.x;   // f4 index, < 16384
        const float* s = wi == 0 ? w0 : wi == 1 ? w1 : wi == 2 ? w2 : wi == 3 ? w3 : wi == 4 ? w4 : w5;
        const float4 v = ((const float4*)s)[i];
        ushort4 o; o.x = f2bf(v.x); o.y = f2bf(v.y); o.z = f2bf(v.z); o.w = f2bf(v.w);
        ((ushort4*)(wbBase + (size_t)wi * 65536))[i] = o;
    } else {
        const int i = (b - nbx - 384) * 256 + threadIdx.x;
        if (i <= N) {
            int lo = 0, hi = E;
            while (lo < hi) { int mid = (lo + hi) >> 1; if (dst[mid] < i) lo = mid + 1; else hi = mid; }
            rp[i] = lo;
        }
    }
}

// ---------------- bucket: per-node, group edges by src>>13 (2MB fp8 buckets) ----------------
// One wave per node. Ballot-compaction: stable within chunk, bucket-major order.
__global__ __launch_bounds__(256) void bucket_kernel(const int* __restrict__ src,
                                                     const int* __restrict__ rp,
                                                     int* __restrict__ srcp, int nNodes) {
    const int node = blockIdx.x * 4 + (threadIdx.x >> 6);
    if (node >= nNodes) return;
    const int lane = threadIdx.x & 63;
    const int beg = __builtin_amdgcn_readfirstlane(rp[node]);
    const int end = __builtin_amdgcn_readfirstlane(rp[node + 1]);
    int base = beg;
    for (int p = 0; p < 16; ++p) {
        for (int c = beg; c < end; c += 64) {
            const int e = c + lane;
            const bool valid = e < end;
            const int s = valid ? src[e] : -1;
            const bool m = valid && ((s >> 13) == p);
            const unsigned long long mask = __ballot(m);
            const int idx = __popcll(mask & ((1ull << lane) - 1ull));
            if (m) srcp[base + idx] = s;
            base += __popcll(mask);
        }
    }
}

// ---------------- fp8 aggregation (R5 structure; src list may be bucketed) ----------------
__global__ __launch_bounds__(256) void agg_fp8_kernel(const uint32_t* __restrict__ h32,  // [N][64] dwords
                                                      const int* __restrict__ src,
                                                      const int* __restrict__ rp,
                                                      unsigned short* __restrict__ mout, int nNodes) {
    const int node = blockIdx.x * 4 + (threadIdx.x >> 6);
    if (node >= nNodes) return;
    const int lane = threadIdx.x & 63;
    const int beg = __builtin_amdgcn_readfirstlane(rp[node]);
    const int end = __builtin_amdgcn_readfirstlane(rp[node + 1]);
    float a0 = 0.f, a1 = 0.f, a2 = 0.f, a3 = 0.f;
    int e = beg;
    for (; e + 8 <= end; e += 8) {
        int s[8];
#pragma unroll
        for (int i = 0; i < 8; i++) s[i] = src[e + i];
        uint32_t w[8];
#pragma unroll
        for (int i = 0; i < 8; i++) w[i] = h32[(size_t)s[i] * 64 + lane];
#pragma unroll
        for (int i = 0; i < 8; i++) {
            a0 += fp8w((w[i] << 20) & 0x07f00000u);
            a1 += fp8w((w[i] << 12) & 0x07f00000u);
            a2 += fp8w((w[i] << 4)  & 0x07f00000u);
            a3 += fp8w((w[i] >> 4)  & 0x07f00000u);
        }
    }
    for (; e < end; ++e) {
        const uint32_t w = h32[(size_t)src[e] * 64 + lane];
        a0 += fp8w((w << 20) & 0x07f00000u);
        a1 += fp8w((w << 12) & 0x07f00000u);
        a2 += fp8w((w << 4)  & 0x07f00000u);
        a3 += fp8w((w >> 4)  & 0x07f00000u);
    }
    const float sc = 0x1p112f;
    ushort4 o;
    o.x = f2bf(a0 * sc); o.y = f2bf(a1 * sc); o.z = f2bf(a2 * sc); o.w = f2bf(a3 * sc);
    *(ushort4*)&mout[(size_t)node * 256 + (size_t)lane * 4] = o;
}

// ---------------- bf16 aggregation (fallback if ws too small for fp8 buffer) ----------------
__global__ __launch_bounds__(256) void agg_kernel(const unsigned short* __restrict__ h,
                                                  const int* __restrict__ src,
                                                  const int* __restrict__ rp,
                                                  unsigned short* __restrict__ mout, int nNodes) {
    const int node = blockIdx.x * 4 + (threadIdx.x >> 6);
    if (node >= nNodes) return;
    const int lane = threadIdx.x & 63;
    const size_t fo = (size_t)lane * 4;
    const int beg = __builtin_amdgcn_readfirstlane(rp[node]);
    const int end = __builtin_amdgcn_readfirstlane(rp[node + 1]);
    float a0 = 0.f, a1 = 0.f, a2 = 0.f, a3 = 0.f;
    int e = beg;
    for (; e + 4 <= end; e += 4) {
        const int s0 = src[e], s1 = src[e+1], s2 = src[e+2], s3 = src[e+3];
        ushort4 v0 = *(const ushort4*)&h[(size_t)s0 * 256 + fo];
        ushort4 v1 = *(const ushort4*)&h[(size_t)s1 * 256 + fo];
        ushort4 v2 = *(const ushort4*)&h[(size_t)s2 * 256 + fo];
        ushort4 v3 = *(const ushort4*)&h[(size_t)s3 * 256 + fo];
        a0 += bf2f(v0.x) + bf2f(v1.x) + bf2f(v2.x) + bf2f(v3.x);
        a1 += bf2f(v0.y) + bf2f(v1.y) + bf2f(v2.y) + bf2f(v3.y);
        a2 += bf2f(v0.z) + bf2f(v1.z) + bf2f(v2.z) + bf2f(v3.z);
        a3 += bf2f(v0.w) + bf2f(v1.w) + bf2f(v2.w) + bf2f(v3.w);
    }
    for (; e < end; ++e) {
        const int s = src[e];
        ushort4 v = *(const ushort4*)&h[(size_t)s * 256 + fo];
        a0 += bf2f(v.x); a1 += bf2f(v.y); a2 += bf2f(v.z); a3 += bf2f(v.w);
    }
    ushort4 o;
    o.x = f2bf(a0); o.y = f2bf(a1); o.z = f2bf(a2); o.w = f2bf(a3);
    *(ushort4*)&mout[(size_t)node * 256 + fo] = o;
}

// ---------------- MFMA GEMM, 2-phase double-buffered ----------------
template <int NSEG, int EPMODE, bool EMIT>
__global__ __launch_bounds__(512) void gemm_kernel(
    const unsigned short* __restrict__ A0, const unsigned short* __restrict__ A1,
    const unsigned short* __restrict__ B0, const unsigned short* __restrict__ B1,
    const float* __restrict__ bias, unsigned short* __restrict__ Out,
    uint8_t* __restrict__ F8, int M) {
    __shared__ unsigned short Alds[2 * 128 * 32];
    __shared__ unsigned short Blds[2 * 256 * 32];
    __shared__ float ssq_lds[8][64];

    const int t = threadIdx.x;
    const int wid = t >> 6;
    const int lane = t & 63;
    const int wr = wid >> 2, wc = wid & 3;
    const int l15 = lane & 15;
    const int kh = lane >> 4;
    const int rowBase = blockIdx.x * 128;

    f4 acc[4][4];
#pragma unroll
    for (int m = 0; m < 4; m++)
#pragma unroll
        for (int n = 0; n < 4; n++) acc[m][n] = f4{0.f, 0.f, 0.f, 0.f};

    const int rA = t >> 2;
    const int sSlotA = (t & 3) ^ ((rA >> 1) & 3);
    int grA = rowBase + rA; if (grA > M - 1) grA = M - 1;
    const size_t gAoff = (size_t)grA * 256 + sSlotA * 8;
    const size_t gBoff0 = (size_t)rA * 256 + sSlotA * 8;
    const size_t gBoff1 = (size_t)(128 + rA) * 256 + sSlotA * 8;

    const int nsteps = NSEG * 8;
    auto STAGE = [&](int s, int buf) {
        const unsigned short* Ap = (NSEG == 2 && s >= 8) ? A1 : A0;
        const unsigned short* Bp = (NSEG == 2 && s >= 8) ? B1 : B0;
        const int k0 = (s & 7) * 32;
        gload16(Ap + gAoff + k0, &Alds[buf * 4096 + wid * 512]);
        gload16(Bp + gBoff0 + k0, &Blds[buf * 8192 + wid * 512]);
        gload16(Bp + gBoff1 + k0, &Blds[buf * 8192 + 4096 + wid * 512]);
    };

    STAGE(0, 0);
    asm volatile("s_waitcnt vmcnt(0)" ::: "memory");
    __syncthreads();

#pragma unroll 2
    for (int s = 0; s < nsteps; ++s) {
        const int cur = s & 1;
        if (s + 1 < nsteps) STAGE(s + 1, cur ^ 1);
        bh8 a[4], b[4];
#pragma unroll
        for (int m = 0; m < 4; m++) {
            const int ra = wr * 64 + m * 16 + l15;
            a[m] = *(const bh8*)&Alds[cur * 4096 + ra * 32 + ((kh ^ ((ra >> 1) & 3)) * 8)];
        }
#pragma unroll
        for (int n = 0; n < 4; n++) {
            const int rb = wc * 64 + n * 16 + l15;
            b[n] = *(const bh8*)&Blds[cur * 8192 + rb * 32 + ((kh ^ ((rb >> 1) & 3)) * 8)];
        }
#pragma unroll
        for (int m = 0; m < 4; m++)
#pragma unroll
            for (int n = 0; n < 4; n++)
                acc[m][n] = __builtin_amdgcn_mfma_f32_16x16x32_bf16(a[m], b[n], acc[m][n], 0, 0, 0);
        asm volatile("s_waitcnt vmcnt(0)" ::: "memory");
        __syncthreads();
    }

    const int cBase = wc * 64 + l15;
    float sq[4][4];
#pragma unroll
    for (int m = 0; m < 4; m++) { sq[m][0] = 0.f; sq[m][1] = 0.f; sq[m][2] = 0.f; sq[m][3] = 0.f; }
#pragma unroll
    for (int n = 0; n < 4; n++) {
        const float bv = bias[cBase + n * 16];
#pragma unroll
        for (int m = 0; m < 4; m++)
#pragma unroll
            for (int r = 0; r < 4; r++) {
                float v = acc[m][n][r] + bv;
                if (EPMODE != 1) v = fmaxf(v, 0.f);
                acc[m][n][r] = v;
                sq[m][r] += v * v;
            }
    }

    if (EPMODE != 2) {
#pragma unroll
        for (int mask = 1; mask < 16; mask <<= 1)
#pragma unroll
            for (int m = 0; m < 4; m++)
#pragma unroll
                for (int r = 0; r < 4; r++) sq[m][r] += __shfl_xor(sq[m][r], mask);
        if (l15 == 0) {
#pragma unroll
            for (int m = 0; m < 4; m++)
#pragma unroll
                for (int r = 0; r < 4; r++) ssq_lds[wid][m * 16 + kh * 4 + r] = sq[m][r];
        }
        __syncthreads();
#pragma unroll
        for (int m = 0; m < 4; m++)
#pragma unroll
            for (int r = 0; r < 4; r++) {
                const int rr = m * 16 + kh * 4 + r;
                const float s = ssq_lds[wr * 4 + 0][rr] + ssq_lds[wr * 4 + 1][rr] +
                                ssq_lds[wr * 4 + 2][rr] + ssq_lds[wr * 4 + 3][rr];
                sq[m][r] = 1.f / fmaxf(sqrtf(s), 1e-12f);
            }
    }

#pragma unroll
    for (int m = 0; m < 4; m++)
#pragma unroll
        for (int r = 0; r < 4; r++) {
            const int grow = rowBase + wr * 64 + m * 16 + kh * 4 + r;
            if (grow < M) {
#pragma unroll
                for (int n = 0; n < 4; n++) {
                    float v = acc[m][n][r];
                    if (EPMODE != 2) v *= sq[m][r];
                    if (EPMODE == 1) v = fmaxf(v, 0.f);
                    Out[(size_t)grow * 256 + cBase + n * 16] = f2bf(v);
                    if (EMIT) F8[(size_t)grow * 256 + cBase + n * 16] = f2fp8(v);
                }
            }
        }
}

// ---------------- final: MFMA logits (100k x 256 @ 256 x 48pad) + fused log_softmax ----------------
__global__ __launch_bounds__(256) void final_kernel(const unsigned short* __restrict__ T,
                                                    const float* __restrict__ Wp,
                                                    const float* __restrict__ bp,
                                                    float* __restrict__ out, int M) {
    __shared__ unsigned short Wlds[48 * 256];   // 24 KB
    const int t = threadIdx.x;
    for (int i = t; i < 48 * 32; i += 256) {
        const int rb = i >> 5, slot = i & 31;
        bh8 o;
        if (rb < 47) {
#pragma unroll
            for (int j = 0; j < 8; j++) o[j] = (short)f2bf(Wp[rb * 256 + slot * 8 + j]);
        } else {
#pragma unroll
            for (int j = 0; j < 8; j++) o[j] = 0;
        }
        *(bh8*)&Wlds[rb * 256 + ((slot ^ (rb & 7)) * 8)] = o;
    }
    __syncthreads();
    const int wave = t >> 6, lane = t & 63;
    const int l15 = lane & 15, kh = lane >> 4;
    const int rowBase = blockIdx.x * 64 + wave * 16;
    int gr = rowBase + l15; if (gr > M - 1) gr = M - 1;

    bh8 a[8];
#pragma unroll
    for (int ks = 0; ks < 8; ks++)
        a[ks] = *(const bh8*)&T[(size_t)gr * 256 + ks * 32 + kh * 8];
    f4 acc[3];
#pragma unroll
    for (int n = 0; n < 3; n++) acc[n] = f4{0.f, 0.f, 0.f, 0.f};
#pragma unroll
    for (int ks = 0; ks < 8; ks++)
#pragma unroll
        for (int n = 0; n < 3; n++) {
            const int rb = n * 16 + l15;
            const bh8 b = *(const bh8*)&Wlds[rb * 256 + (((ks * 4 + kh) ^ (rb & 7)) * 8)];
            acc[n] = __builtin_amdgcn_mfma_f32_16x16x32_bf16(a[ks], b, acc[n], 0, 0, 0);
        }

    const int c0 = l15, c1 = 16 + l15, c2 = 32 + l15;
    const float b0 = bp[c0], b1 = bp[c1];
    const float b2 = (l15 < 15) ? bp[c2] : 0.f;
#pragma unroll
    for (int r = 0; r < 4; r++) {
        const int grow = rowBase + kh * 4 + r;
        const float x0 = acc[0][r] + b0;
        const float x1 = acc[1][r] + b1;
        const float x2 = (l15 < 15) ? (acc[2][r] + b2) : -3.0e38f;
        float mx = fmaxf(fmaxf(x0, x1), x2);
#pragma unroll
        for (int msk = 1; msk < 16; msk <<= 1) mx = fmaxf(mx, __shfl_xor(mx, msk));
        float se = __expf(x0 - mx) + __expf(x1 - mx) + ((l15 < 15) ? __expf(x2 - mx) : 0.f);
#pragma unroll
        for (int msk = 1; msk < 16; msk <<= 1) se += __shfl_xor(se, msk);
        const float ls = __logf(se) + mx;
        if (grow < M) {
            float* orow = &out[(size_t)grow * 47];
            orow[c0] = x0 - ls;
            orow[c1] = x1 - ls;
            if (l15 < 15) orow[c2] = x2 - ls;
        }
    }
}

extern "C" void kernel_launch(void* const* d_in, const int* in_sizes, int n_in,
                              void* d_out, int out_size, void* d_ws, size_t ws_size,
                              hipStream_t stream) {
    const float* x      = (const float*)d_in[0];
    const int*   src    = (const int*)d_in[1];
    const int*   dst    = (const int*)d_in[2];
    const float* W_pre  = (const float*)d_in[3];
    const float* b_pre  = (const float*)d_in[4];
    const float* Wl1    = (const float*)d_in[5];
    const float* bl1    = (const float*)d_in[6];
    const float* Wr1    = (const float*)d_in[7];
    const float* Wl2    = (const float*)d_in[8];
    const float* bl2    = (const float*)d_in[9];
    const float* Wr2    = (const float*)d_in[10];
    const float* W_jk   = (const float*)d_in[11];
    const float* b_jk   = (const float*)d_in[12];
    const float* W_post = (const float*)d_in[13];
    const float* b_post = (const float*)d_in[14];

    const int N = in_sizes[0] / 256;
    const int E = in_sizes[1];

    char* ws = (char*)d_ws;
    char* ws0 = ws;
    const size_t HB = (size_t)N * 256 * 2;
    unsigned short* bufA = (unsigned short*)ws; ws += HB;   // xb -> h2
    unsigned short* bufB = (unsigned short*)ws; ws += HB;   // h0 -> t
    unsigned short* bufC = (unsigned short*)ws; ws += HB;   // m1 -> m2
    unsigned short* bufD = (unsigned short*)ws; ws += HB;   // h1
    unsigned short* wbBase = (unsigned short*)ws; ws += (size_t)6 * 65536 * 2;
    int* rp = (int*)ws; ws += (size_t)(N + 1) * 4;
    uint8_t* f8 = (uint8_t*)ws; ws += (size_t)N * 256;      // shared fp8 buffer (h0 then h1)
    const bool useFp8 = ((size_t)(ws - ws0) <= ws_size);
    int* srcp = (int*)ws; ws += (size_t)E * 4;              // bucketed edge list
    const bool useSort = useFp8 && ((size_t)(ws - ws0) <= ws_size);

    const int n4x = (N * 256) / 4;
    const int nbx = (n4x + 255) / 256;
    const int nbr = (N + 1 + 255) / 256;
    prep_kernel<<<nbx + 384 + nbr, 256, 0, stream>>>(x, bufA, n4x, nbx,
        W_pre, Wl1, Wr1, Wl2, Wr2, W_jk, wbBase, dst, rp, N, E);
    unsigned short* wb[6];
    for (int i = 0; i < 6; i++) wb[i] = wbBase + (size_t)i * 65536;

    const int gB = (N + 127) / 128;
    const int gAgg = (N + 3) / 4;
    if (useFp8) {
        const int* srcUse = useSort ? srcp : src;
        if (useSort) bucket_kernel<<<gAgg, 256, 0, stream>>>(src, rp, srcp, N);
        gemm_kernel<1, 0, true><<<gB, 512, 0, stream>>>(bufA, nullptr, wb[0], nullptr, b_pre, bufB, f8, N);
        agg_fp8_kernel<<<gAgg, 256, 0, stream>>>((const uint32_t*)f8, srcUse, rp, bufC, N);
        gemm_kernel<2, 1, true><<<gB, 512, 0, stream>>>(bufC, bufB, wb[1], wb[2], bl1, bufD, f8, N);
        agg_fp8_kernel<<<gAgg, 256, 0, stream>>>((const uint32_t*)f8, srcUse, rp, bufC, N);
        gemm_kernel<2, 1, false><<<gB, 512, 0, stream>>>(bufC, bufD, wb[3], wb[4], bl2, bufA, nullptr, N);
        gemm_kernel<1, 2, false><<<gB, 512, 0, stream>>>(bufA, nullptr, wb[5], nullptr, b_jk, bufB, nullptr, N);
    } else {
        gemm_kernel<1, 0, false><<<gB, 512, 0, stream>>>(bufA, nullptr, wb[0], nullptr, b_pre, bufB, nullptr, N);
        agg_kernel<<<gAgg, 256, 0, stream>>>(bufB, src, rp, bufC, N);
        gemm_kernel<2, 1, false><<<gB, 512, 0, stream>>>(bufC, bufB, wb[1], wb[2], bl1, bufD, nullptr, N);
        agg_kernel<<<gAgg, 256, 0, stream>>>(bufD, src, rp, bufC, N);
        gemm_kernel<2, 1, false><<<gB, 512, 0, stream>>>(bufC, bufD, wb[3], wb[4], bl2, bufA, nullptr, N);
        gemm_kernel<1, 2, false><<<gB, 512, 0, stream>>>(bufA, nullptr, wb[5], nullptr, b_jk, bufB, nullptr, N);
    }
    final_kernel<<<(N + 63) / 64, 256, 0, stream>>>(bufB, W_post, b_post, (float*)d_out, N);
}

// Round 9
// 587.346 us; speedup vs baseline: 1.1571x; 1.1571x over previous
//
#include <hip/hip_runtime.h>
#include <stdint.h>

#define DEV __device__ __forceinline__

typedef __attribute__((ext_vector_type(8))) short bh8;
typedef __attribute__((ext_vector_type(4))) float f4;
#define LDS_AS __attribute__((address_space(3)))
#define GLB_AS __attribute__((address_space(1)))

DEV unsigned short f2bf(float f) {
    union { float f; uint32_t u; } c; c.f = f;
    uint32_t u = c.u;
    uint32_t r = (u + 0x7fffu + ((u >> 16) & 1u)) >> 16;
    return (unsigned short)r;
}
DEV float bf2f(unsigned short h) {
    union { uint32_t u; float f; } c; c.u = ((uint32_t)h) << 16;
    return c.f;
}

// fp8 e4m3 (non-negative only), stored value = v * 256 (v in [0, ~1]).
DEV uint8_t f2fp8(float v) {
    const float vs = v * 256.f;
    union { float f; uint32_t u; } c; c.f = vs;
    const uint32_t u = c.u + 0x7ffffu + ((c.u >> 20) & 1u);
    const uint32_t f8 = (u >> 20) - 960u;            // ((e8-120)<<3)|m3
    return (vs < 0.015625f) ? (uint8_t)0 : (uint8_t)f8;
}
DEV float fp8w(uint32_t x) { union { uint32_t u; float f; } c; c.u = x; return c.f; }

DEV void gload16(const void* g, void* l) {
    __builtin_amdgcn_global_load_lds((const GLB_AS uint32_t*)g, (LDS_AS uint32_t*)l, 16, 0, 0);
}

// ---------------- prep: 6 weight-cvts + rowptr ----------------
__global__ __launch_bounds__(256) void prep_kernel(
    const float* __restrict__ w0, const float* __restrict__ w1, const float* __restrict__ w2,
    const float* __restrict__ w3, const float* __restrict__ w4, const float* __restrict__ w5,
    unsigned short* __restrict__ wbBase,
    const int* __restrict__ dst, int* __restrict__ rp, int N, int E) {
    const int b = blockIdx.x;
    if (b < 384) {
        const int wi = b >> 6;
        const int i = (b & 63) * 256 + threadIdx.x;   // f4 index, < 16384
        const float* s = wi == 0 ? w0 : wi == 1 ? w1 : wi == 2 ? w2 : wi == 3 ? w3 : wi == 4 ? w4 : w5;
        const float4 v = ((const float4*)s)[i];
        ushort4 o; o.x = f2bf(v.x); o.y = f2bf(v.y); o.z = f2bf(v.z); o.w = f2bf(v.w);
        ((ushort4*)(wbBase + (size_t)wi * 65536))[i] = o;
    } else {
        const int i = (b - 384) * 256 + threadIdx.x;
        if (i <= N) {
            int lo = 0, hi = E;
            while (lo < hi) { int mid = (lo + hi) >> 1; if (dst[mid] < i) lo = mid + 1; else hi = mid; }
            rp[i] = lo;
        }
    }
}

// ---------------- fp8 aggregation (R5 structure — measured floor ~150us) ----------------
__global__ __launch_bounds__(256) void agg_fp8_kernel(const uint32_t* __restrict__ h32,  // [N][64] dwords
                                                      const int* __restrict__ src,
                                                      const int* __restrict__ rp,
                                                      unsigned short* __restrict__ mout, int nNodes) {
    const int node = blockIdx.x * 4 + (threadIdx.x >> 6);
    if (node >= nNodes) return;
    const int lane = threadIdx.x & 63;
    const int beg = __builtin_amdgcn_readfirstlane(rp[node]);
    const int end = __builtin_amdgcn_readfirstlane(rp[node + 1]);
    float a0 = 0.f, a1 = 0.f, a2 = 0.f, a3 = 0.f;
    int e = beg;
    for (; e + 8 <= end; e += 8) {
        int s[8];
#pragma unroll
        for (int i = 0; i < 8; i++) s[i] = src[e + i];
        uint32_t w[8];
#pragma unroll
        for (int i = 0; i < 8; i++) w[i] = h32[(size_t)s[i] * 64 + lane];
#pragma unroll
        for (int i = 0; i < 8; i++) {
            a0 += fp8w((w[i] << 20) & 0x07f00000u);
            a1 += fp8w((w[i] << 12) & 0x07f00000u);
            a2 += fp8w((w[i] << 4)  & 0x07f00000u);
            a3 += fp8w((w[i] >> 4)  & 0x07f00000u);
        }
    }
    for (; e < end; ++e) {
        const uint32_t w = h32[(size_t)src[e] * 64 + lane];
        a0 += fp8w((w << 20) & 0x07f00000u);
        a1 += fp8w((w << 12) & 0x07f00000u);
        a2 += fp8w((w << 4)  & 0x07f00000u);
        a3 += fp8w((w >> 4)  & 0x07f00000u);
    }
    const float sc = 0x1p112f;
    ushort4 o;
    o.x = f2bf(a0 * sc); o.y = f2bf(a1 * sc); o.z = f2bf(a2 * sc); o.w = f2bf(a3 * sc);
    *(ushort4*)&mout[(size_t)node * 256 + (size_t)lane * 4] = o;
}

// ---------------- bf16 aggregation (fallback if ws too small for fp8 buffer) ----------------
__global__ __launch_bounds__(256) void agg_kernel(const unsigned short* __restrict__ h,
                                                  const int* __restrict__ src,
                                                  const int* __restrict__ rp,
                                                  unsigned short* __restrict__ mout, int nNodes) {
    const int node = blockIdx.x * 4 + (threadIdx.x >> 6);
    if (node >= nNodes) return;
    const int lane = threadIdx.x & 63;
    const size_t fo = (size_t)lane * 4;
    const int beg = __builtin_amdgcn_readfirstlane(rp[node]);
    const int end = __builtin_amdgcn_readfirstlane(rp[node + 1]);
    float a0 = 0.f, a1 = 0.f, a2 = 0.f, a3 = 0.f;
    int e = beg;
    for (; e + 4 <= end; e += 4) {
        const int s0 = src[e], s1 = src[e+1], s2 = src[e+2], s3 = src[e+3];
        ushort4 v0 = *(const ushort4*)&h[(size_t)s0 * 256 + fo];
        ushort4 v1 = *(const ushort4*)&h[(size_t)s1 * 256 + fo];
        ushort4 v2 = *(const ushort4*)&h[(size_t)s2 * 256 + fo];
        ushort4 v3 = *(const ushort4*)&h[(size_t)s3 * 256 + fo];
        a0 += bf2f(v0.x) + bf2f(v1.x) + bf2f(v2.x) + bf2f(v3.x);
        a1 += bf2f(v0.y) + bf2f(v1.y) + bf2f(v2.y) + bf2f(v3.y);
        a2 += bf2f(v0.z) + bf2f(v1.z) + bf2f(v2.z) + bf2f(v3.z);
        a3 += bf2f(v0.w) + bf2f(v1.w) + bf2f(v2.w) + bf2f(v3.w);
    }
    for (; e < end; ++e) {
        const int s = src[e];
        ushort4 v = *(const ushort4*)&h[(size_t)s * 256 + fo];
        a0 += bf2f(v.x); a1 += bf2f(v.y); a2 += bf2f(v.z); a3 += bf2f(v.w);
    }
    ushort4 o;
    o.x = f2bf(a0); o.y = f2bf(a1); o.z = f2bf(a2); o.w = f2bf(a3);
    *(ushort4*)&mout[(size_t)node * 256 + fo] = o;
}

// ---------------- MFMA GEMM, 2-phase double-buffered; optional f32-A conversion ----------------
// CVT: A0 is f32; stage A via reg (2x float4 -> cvt -> ds_write_b128 at the linear slot).
template <int NSEG, int EPMODE, bool EMIT, bool CVT>
__global__ __launch_bounds__(512) void gemm_kernel(
    const void* __restrict__ A0v, const unsigned short* __restrict__ A1,
    const unsigned short* __restrict__ B0, const unsigned short* __restrict__ B1,
    const float* __restrict__ bias, unsigned short* __restrict__ Out,
    uint8_t* __restrict__ F8, int M) {
    __shared__ unsigned short Alds[2 * 128 * 32];
    __shared__ unsigned short Blds[2 * 256 * 32];
    __shared__ float ssq_lds[8][64];

    const unsigned short* A0 = (const unsigned short*)A0v;
    const float* A0f = (const float*)A0v;

    const int t = threadIdx.x;
    const int wid = t >> 6;
    const int lane = t & 63;
    const int wr = wid >> 2, wc = wid & 3;
    const int l15 = lane & 15;
    const int kh = lane >> 4;
    const int rowBase = blockIdx.x * 128;

    f4 acc[4][4];
#pragma unroll
    for (int m = 0; m < 4; m++)
#pragma unroll
        for (int n = 0; n < 4; n++) acc[m][n] = f4{0.f, 0.f, 0.f, 0.f};

    const int rA = t >> 2;
    const int sSlotA = (t & 3) ^ ((rA >> 1) & 3);
    int grA = rowBase + rA; if (grA > M - 1) grA = M - 1;
    const size_t gAoff = (size_t)grA * 256 + sSlotA * 8;
    const size_t gBoff0 = (size_t)rA * 256 + sSlotA * 8;
    const size_t gBoff1 = (size_t)(128 + rA) * 256 + sSlotA * 8;

    const int nsteps = NSEG * 8;
    auto STAGE = [&](int s, int buf) {
        const unsigned short* Bp = (NSEG == 2 && s >= 8) ? B1 : B0;
        const int k0 = (s & 7) * 32;
        if (CVT) {
            const float* Af = A0f + gAoff + k0;
            const float4 v0 = *(const float4*)Af;
            const float4 v1 = *(const float4*)(Af + 4);
            bh8 o;
            o[0] = (short)f2bf(v0.x); o[1] = (short)f2bf(v0.y);
            o[2] = (short)f2bf(v0.z); o[3] = (short)f2bf(v0.w);
            o[4] = (short)f2bf(v1.x); o[5] = (short)f2bf(v1.y);
            o[6] = (short)f2bf(v1.z); o[7] = (short)f2bf(v1.w);
            *(bh8*)&Alds[buf * 4096 + wid * 512 + lane * 8] = o;
        } else {
            const unsigned short* Ap = (NSEG == 2 && s >= 8) ? A1 : A0;
            gload16(Ap + gAoff + k0, &Alds[buf * 4096 + wid * 512]);
        }
        gload16(Bp + gBoff0 + k0, &Blds[buf * 8192 + wid * 512]);
        gload16(Bp + gBoff1 + k0, &Blds[buf * 8192 + 4096 + wid * 512]);
    };

    STAGE(0, 0);
    asm volatile("s_waitcnt vmcnt(0)" ::: "memory");
    __syncthreads();

#pragma unroll 2
    for (int s = 0; s < nsteps; ++s) {
        const int cur = s & 1;
        if (s + 1 < nsteps) STAGE(s + 1, cur ^ 1);
        bh8 a[4], b[4];
#pragma unroll
        for (int m = 0; m < 4; m++) {
            const int ra = wr * 64 + m * 16 + l15;
            a[m] = *(const bh8*)&Alds[cur * 4096 + ra * 32 + ((kh ^ ((ra >> 1) & 3)) * 8)];
        }
#pragma unroll
        for (int n = 0; n < 4; n++) {
            const int rb = wc * 64 + n * 16 + l15;
            b[n] = *(const bh8*)&Blds[cur * 8192 + rb * 32 + ((kh ^ ((rb >> 1) & 3)) * 8)];
        }
#pragma unroll
        for (int m = 0; m < 4; m++)
#pragma unroll
            for (int n = 0; n < 4; n++)
                acc[m][n] = __builtin_amdgcn_mfma_f32_16x16x32_bf16(a[m], b[n], acc[m][n], 0, 0, 0);
        asm volatile("s_waitcnt vmcnt(0)" ::: "memory");
        __syncthreads();
    }

    const int cBase = wc * 64 + l15;
    float sq[4][4];
#pragma unroll
    for (int m = 0; m < 4; m++) { sq[m][0] = 0.f; sq[m][1] = 0.f; sq[m][2] = 0.f; sq[m][3] = 0.f; }
#pragma unroll
    for (int n = 0; n < 4; n++) {
        const float bv = bias[cBase + n * 16];
#pragma unroll
        for (int m = 0; m < 4; m++)
#pragma unroll
            for (int r = 0; r < 4; r++) {
                float v = acc[m][n][r] + bv;
                if (EPMODE != 1) v = fmaxf(v, 0.f);
                acc[m][n][r] = v;
                sq[m][r] += v * v;
            }
    }

    if (EPMODE != 2) {
#pragma unroll
        for (int mask = 1; mask < 16; mask <<= 1)
#pragma unroll
            for (int m = 0; m < 4; m++)
#pragma unroll
                for (int r = 0; r < 4; r++) sq[m][r] += __shfl_xor(sq[m][r], mask);
        if (l15 == 0) {
#pragma unroll
            for (int m = 0; m < 4; m++)
#pragma unroll
                for (int r = 0; r < 4; r++) ssq_lds[wid][m * 16 + kh * 4 + r] = sq[m][r];
        }
        __syncthreads();
#pragma unroll
        for (int m = 0; m < 4; m++)
#pragma unroll
            for (int r = 0; r < 4; r++) {
                const int rr = m * 16 + kh * 4 + r;
                const float s = ssq_lds[wr * 4 + 0][rr] + ssq_lds[wr * 4 + 1][rr] +
                                ssq_lds[wr * 4 + 2][rr] + ssq_lds[wr * 4 + 3][rr];
                sq[m][r] = 1.f / fmaxf(sqrtf(s), 1e-12f);
            }
    }

#pragma unroll
    for (int m = 0; m < 4; m++)
#pragma unroll
        for (int r = 0; r < 4; r++) {
            const int grow = rowBase + wr * 64 + m * 16 + kh * 4 + r;
            if (grow < M) {
#pragma unroll
                for (int n = 0; n < 4; n++) {
                    float v = acc[m][n][r];
                    if (EPMODE != 2) v *= sq[m][r];
                    if (EPMODE == 1) v = fmaxf(v, 0.f);
                    Out[(size_t)grow * 256 + cBase + n * 16] = f2bf(v);
                    if (EMIT) F8[(size_t)grow * 256 + cBase + n * 16] = f2fp8(v);
                }
            }
        }
}

// ---------------- fused JK GEMM + post-classifier + log_softmax ----------------
// BM=64, 4 waves. Phase 1: t = relu(h2 @ Wjk^T + bjk) -> swizzled Tlds (32KB).
// Phase 2: S (staging, 40KB) is reused for W_post bf16; logits MFMA + softmax.
__global__ __launch_bounds__(256) void jkfinal_kernel(
    const unsigned short* __restrict__ A,     // h2 bf16 [M][256]
    const unsigned short* __restrict__ Bjk,   // W_jk bf16 [256][256]
    const float* __restrict__ bjk,
    const float* __restrict__ Wp, const float* __restrict__ bp,
    float* __restrict__ out, int M) {
    __shared__ unsigned short S[20480];       // A dbuf 2x2048 | B dbuf 2x8192 ; reused as Wlds
    __shared__ unsigned short Tlds[64 * 256]; // swizzled t tile

    const int t = threadIdx.x;
    const int wid = t >> 6;
    const int lane = t & 63;
    const int wc = wid;                        // 4 col strips of 64
    const int l15 = lane & 15;
    const int kh = lane >> 4;
    const int rowBase = blockIdx.x * 64;

    f4 acc[4][4];
#pragma unroll
    for (int m = 0; m < 4; m++)
#pragma unroll
        for (int n = 0; n < 4; n++) acc[m][n] = f4{0.f, 0.f, 0.f, 0.f};

    const int rA = t >> 2;                     // 0..63
    const int sSlotA = (t & 3) ^ ((rA >> 1) & 3);
    int grA = rowBase + rA; if (grA > M - 1) grA = M - 1;
    const size_t gAoff = (size_t)grA * 256 + sSlotA * 8;
    const size_t gBoff = (size_t)rA * 256 + sSlotA * 8;

    auto STAGE = [&](int s, int buf) {
        const int k0 = s * 32;
        gload16(A + gAoff + k0, &S[buf * 2048 + wid * 512]);
#pragma unroll
        for (int p = 0; p < 4; ++p)
            gload16(Bjk + (size_t)p * 16384 + gBoff + k0,
                    &S[4096 + buf * 8192 + p * 2048 + wid * 512]);
    };

    STAGE(0, 0);
    asm volatile("s_waitcnt vmcnt(0)" ::: "memory");
    __syncthreads();

#pragma unroll 2
    for (int s = 0; s < 8; ++s) {
        const int cur = s & 1;
        if (s + 1 < 8) STAGE(s + 1, cur ^ 1);
        bh8 a[4], b[4];
#pragma unroll
        for (int m = 0; m < 4; m++) {
            const int ra = m * 16 + l15;
            a[m] = *(const bh8*)&S[cur * 2048 + ra * 32 + ((kh ^ ((ra >> 1) & 3)) * 8)];
        }
#pragma unroll
        for (int n = 0; n < 4; n++) {
            const int rb = wc * 64 + n * 16 + l15;
            b[n] = *(const bh8*)&S[4096 + cur * 8192 + rb * 32 + ((kh ^ ((rb >> 1) & 3)) * 8)];
        }
#pragma unroll
        for (int m = 0; m < 4; m++)
#pragma unroll
            for (int n = 0; n < 4; n++)
                acc[m][n] = __builtin_amdgcn_mfma_f32_16x16x32_bf16(a[m], b[n], acc[m][n], 0, 0, 0);
        asm volatile("s_waitcnt vmcnt(0)" ::: "memory");
        __syncthreads();
    }

    // phase-1 epilogue: relu(+bias) -> Tlds, swizzled: addr(row,c) = row*256 + ((c>>4 ^ (row>>2)&7)<<4 | c&15)
    const int cBase = wc * 64 + l15;
#pragma unroll
    for (int n = 0; n < 4; n++) {
        const float bv = bjk[cBase + n * 16];
        const int slot = wc * 4 + n;
#pragma unroll
        for (int m = 0; m < 4; m++)
#pragma unroll
            for (int r = 0; r < 4; r++) {
                const int row = m * 16 + kh * 4 + r;
                const float v = fmaxf(acc[m][n][r] + bv, 0.f);
                Tlds[row * 256 + (((slot ^ ((row >> 2) & 7)) << 4) | l15)] = f2bf(v);
            }
    }
    // load W_post into S (staging reads all retired at loop-end barrier)
    for (int i = t; i < 48 * 32; i += 256) {
        const int rb = i >> 5, slot = i & 31;
        bh8 o;
        if (rb < 47) {
#pragma unroll
            for (int j = 0; j < 8; j++) o[j] = (short)f2bf(Wp[rb * 256 + slot * 8 + j]);
        } else {
#pragma unroll
            for (int j = 0; j < 8; j++) o[j] = 0;
        }
        *(bh8*)&S[rb * 256 + ((slot ^ (rb & 7)) * 8)] = o;
    }
    __syncthreads();

    // phase 2: wave wid owns rows [wid*16, wid*16+16)
    const int lrow = wid * 16 + l15;
    bh8 a2[8];
#pragma unroll
    for (int ks = 0; ks < 8; ks++) {
        const int slot = ks * 2 + (kh >> 1);
        a2[ks] = *(const bh8*)&Tlds[lrow * 256 + (((slot ^ ((lrow >> 2) & 7)) << 4) | ((kh & 1) * 8))];
    }
    f4 acc2[3];
#pragma unroll
    for (int n = 0; n < 3; n++) acc2[n] = f4{0.f, 0.f, 0.f, 0.f};
#pragma unroll
    for (int ks = 0; ks < 8; ks++)
#pragma unroll
        for (int n = 0; n < 3; n++) {
            const int rb = n * 16 + l15;
            const bh8 b = *(const bh8*)&S[rb * 256 + (((ks * 4 + kh) ^ (rb & 7)) * 8)];
            acc2[n] = __builtin_amdgcn_mfma_f32_16x16x32_bf16(a2[ks], b, acc2[n], 0, 0, 0);
        }

    const int c0 = l15, c1 = 16 + l15, c2 = 32 + l15;
    const float b0 = bp[c0], b1 = bp[c1];
    const float b2 = (l15 < 15) ? bp[c2] : 0.f;
#pragma unroll
    for (int r = 0; r < 4; r++) {
        const int grow = rowBase + wid * 16 + kh * 4 + r;
        const float x0 = acc2[0][r] + b0;
        const float x1 = acc2[1][r] + b1;
        const float x2 = (l15 < 15) ? (acc2[2][r] + b2) : -3.0e38f;
        float mx = fmaxf(fmaxf(x0, x1), x2);
#pragma unroll
        for (int msk = 1; msk < 16; msk <<= 1) mx = fmaxf(mx, __shfl_xor(mx, msk));
        float se = __expf(x0 - mx) + __expf(x1 - mx) + ((l15 < 15) ? __expf(x2 - mx) : 0.f);
#pragma unroll
        for (int msk = 1; msk < 16; msk <<= 1) se += __shfl_xor(se, msk);
        const float ls = __logf(se) + mx;
        if (grow < M) {
            float* orow = &out[(size_t)grow * 47];
            orow[c0] = x0 - ls;
            orow[c1] = x1 - ls;
            if (l15 < 15) orow[c2] = x2 - ls;
        }
    }
}

extern "C" void kernel_launch(void* const* d_in, const int* in_sizes, int n_in,
                              void* d_out, int out_size, void* d_ws, size_t ws_size,
                              hipStream_t stream) {
    const float* x      = (const float*)d_in[0];
    const int*   src    = (const int*)d_in[1];
    const int*   dst    = (const int*)d_in[2];
    const float* W_pre  = (const float*)d_in[3];
    const float* b_pre  = (const float*)d_in[4];
    const float* Wl1    = (const float*)d_in[5];
    const float* bl1    = (const float*)d_in[6];
    const float* Wr1    = (const float*)d_in[7];
    const float* Wl2    = (const float*)d_in[8];
    const float* bl2    = (const float*)d_in[9];
    const float* Wr2    = (const float*)d_in[10];
    const float* W_jk   = (const float*)d_in[11];
    const float* b_jk   = (const float*)d_in[12];
    const float* W_post = (const float*)d_in[13];
    const float* b_post = (const float*)d_in[14];

    const int N = in_sizes[0] / 256;
    const int E = in_sizes[1];

    char* ws = (char*)d_ws;
    char* ws0 = ws;
    const size_t HB = (size_t)N * 256 * 2;
    unsigned short* bufA = (unsigned short*)ws; ws += HB;   // h2
    unsigned short* bufB = (unsigned short*)ws; ws += HB;   // h0
    unsigned short* bufC = (unsigned short*)ws; ws += HB;   // m1 -> m2
    unsigned short* bufD = (unsigned short*)ws; ws += HB;   // h1
    unsigned short* wbBase = (unsigned short*)ws; ws += (size_t)6 * 65536 * 2;
    int* rp = (int*)ws; ws += (size_t)(N + 1) * 4;
    uint8_t* f8 = (uint8_t*)ws; ws += (size_t)N * 256;      // shared fp8 buffer (h0 then h1)
    const bool useFp8 = ((size_t)(ws - ws0) <= ws_size);

    const int nbr = (N + 1 + 255) / 256;
    prep_kernel<<<384 + nbr, 256, 0, stream>>>(W_pre, Wl1, Wr1, Wl2, Wr2, W_jk,
                                               wbBase, dst, rp, N, E);
    unsigned short* wb[6];
    for (int i = 0; i < 6; i++) wb[i] = wbBase + (size_t)i * 65536;

    const int gB = (N + 127) / 128;
    const int gAgg = (N + 3) / 4;
    if (useFp8) {
        gemm_kernel<1, 0, true, true><<<gB, 512, 0, stream>>>(x, nullptr, wb[0], nullptr, b_pre, bufB, f8, N);
        agg_fp8_kernel<<<gAgg, 256, 0, stream>>>((const uint32_t*)f8, src, rp, bufC, N);
        gemm_kernel<2, 1, true, false><<<gB, 512, 0, stream>>>(bufC, bufB, wb[1], wb[2], bl1, bufD, f8, N);
        agg_fp8_kernel<<<gAgg, 256, 0, stream>>>((const uint32_t*)f8, src, rp, bufC, N);
        gemm_kernel<2, 1, false, false><<<gB, 512, 0, stream>>>(bufC, bufD, wb[3], wb[4], bl2, bufA, nullptr, N);
    } else {
        gemm_kernel<1, 0, false, true><<<gB, 512, 0, stream>>>(x, nullptr, wb[0], nullptr, b_pre, bufB, nullptr, N);
        agg_kernel<<<gAgg, 256, 0, stream>>>(bufB, src, rp, bufC, N);
        gemm_kernel<2, 1, false, false><<<gB, 512, 0, stream>>>(bufC, bufB, wb[1], wb[2], bl1, bufD, nullptr, N);
        agg_kernel<<<gAgg, 256, 0, stream>>>(bufD, src, rp, bufC, N);
        gemm_kernel<2, 1, false, false><<<gB, 512, 0, stream>>>(bufC, bufD, wb[3], wb[4], bl2, bufA, nullptr, N);
    }
    jkfinal_kernel<<<(N + 63) / 64, 256, 0, stream>>>(bufA, wb[5], b_jk, W_post, b_post,
                                                      (float*)d_out, N);
}

// Round 10
// 573.822 us; speedup vs baseline: 1.1843x; 1.0236x over previous
//
#include <hip/hip_runtime.h>
#include <stdint.h>

#define DEV __device__ __forceinline__

typedef __attribute__((ext_vector_type(8))) short bh8;
typedef __attribute__((ext_vector_type(4))) float f4;
#define LDS_AS __attribute__((address_space(3)))
#define GLB_AS __attribute__((address_space(1)))

DEV unsigned short f2bf(float f) {
    union { float f; uint32_t u; } c; c.f = f;
    uint32_t u = c.u;
    uint32_t r = (u + 0x7fffu + ((u >> 16) & 1u)) >> 16;
    return (unsigned short)r;
}
DEV float bf2f(unsigned short h) {
    union { uint32_t u; float f; } c; c.u = ((uint32_t)h) << 16;
    return c.f;
}

// fp8 e4m3 (non-negative only), stored value = v * 256 (v in [0, ~1]).
DEV uint8_t f2fp8(float v) {
    const float vs = v * 256.f;
    union { float f; uint32_t u; } c; c.f = vs;
    const uint32_t u = c.u + 0x7ffffu + ((c.u >> 20) & 1u);
    const uint32_t f8 = (u >> 20) - 960u;            // ((e8-120)<<3)|m3
    return (vs < 0.015625f) ? (uint8_t)0 : (uint8_t)f8;
}
DEV float fp8w(uint32_t x) { union { uint32_t u; float f; } c; c.u = x; return c.f; }
// fp8 (our encoding) -> bf16 of the true value v: exp field e8-8, 3->7 mantissa shift.
DEV unsigned short fp82bf(uint32_t f) {
    return f ? (unsigned short)((f << 4) + 0x3800u) : (unsigned short)0;
}

DEV void gload16(const void* g, void* l) {
    __builtin_amdgcn_global_load_lds((const GLB_AS uint32_t*)g, (LDS_AS uint32_t*)l, 16, 0, 0);
}

// ---------------- prep: 6 weight-cvts + rowptr ----------------
__global__ __launch_bounds__(256) void prep_kernel(
    const float* __restrict__ w0, const float* __restrict__ w1, const float* __restrict__ w2,
    const float* __restrict__ w3, const float* __restrict__ w4, const float* __restrict__ w5,
    unsigned short* __restrict__ wbBase,
    const int* __restrict__ dst, int* __restrict__ rp, int N, int E) {
    const int b = blockIdx.x;
    if (b < 384) {
        const int wi = b >> 6;
        const int i = (b & 63) * 256 + threadIdx.x;   // f4 index, < 16384
        const float* s = wi == 0 ? w0 : wi == 1 ? w1 : wi == 2 ? w2 : wi == 3 ? w3 : wi == 4 ? w4 : w5;
        const float4 v = ((const float4*)s)[i];
        ushort4 o; o.x = f2bf(v.x); o.y = f2bf(v.y); o.z = f2bf(v.z); o.w = f2bf(v.w);
        ((ushort4*)(wbBase + (size_t)wi * 65536))[i] = o;
    } else {
        const int i = (b - 384) * 256 + threadIdx.x;
        if (i <= N) {
            int lo = 0, hi = E;
            while (lo < hi) { int mid = (lo + hi) >> 1; if (dst[mid] < i) lo = mid + 1; else hi = mid; }
            rp[i] = lo;
        }
    }
}

// ---------------- fp8 aggregation (R5 structure — measured floor ~150us) ----------------
__global__ __launch_bounds__(256) void agg_fp8_kernel(const uint32_t* __restrict__ h32,  // [N][64] dwords
                                                      const int* __restrict__ src,
                                                      const int* __restrict__ rp,
                                                      unsigned short* __restrict__ mout, int nNodes) {
    const int node = blockIdx.x * 4 + (threadIdx.x >> 6);
    if (node >= nNodes) return;
    const int lane = threadIdx.x & 63;
    const int beg = __builtin_amdgcn_readfirstlane(rp[node]);
    const int end = __builtin_amdgcn_readfirstlane(rp[node + 1]);
    float a0 = 0.f, a1 = 0.f, a2 = 0.f, a3 = 0.f;
    int e = beg;
    for (; e + 8 <= end; e += 8) {
        int s[8];
#pragma unroll
        for (int i = 0; i < 8; i++) s[i] = src[e + i];
        uint32_t w[8];
#pragma unroll
        for (int i = 0; i < 8; i++) w[i] = h32[(size_t)s[i] * 64 + lane];
#pragma unroll
        for (int i = 0; i < 8; i++) {
            a0 += fp8w((w[i] << 20) & 0x07f00000u);
            a1 += fp8w((w[i] << 12) & 0x07f00000u);
            a2 += fp8w((w[i] << 4)  & 0x07f00000u);
            a3 += fp8w((w[i] >> 4)  & 0x07f00000u);
        }
    }
    for (; e < end; ++e) {
        const uint32_t w = h32[(size_t)src[e] * 64 + lane];
        a0 += fp8w((w << 20) & 0x07f00000u);
        a1 += fp8w((w << 12) & 0x07f00000u);
        a2 += fp8w((w << 4)  & 0x07f00000u);
        a3 += fp8w((w >> 4)  & 0x07f00000u);
    }
    const float sc = 0x1p112f;
    ushort4 o;
    o.x = f2bf(a0 * sc); o.y = f2bf(a1 * sc); o.z = f2bf(a2 * sc); o.w = f2bf(a3 * sc);
    *(ushort4*)&mout[(size_t)node * 256 + (size_t)lane * 4] = o;
}

// ---------------- bf16 aggregation (fallback if ws too small for fp8 buffer) ----------------
__global__ __launch_bounds__(256) void agg_kernel(const unsigned short* __restrict__ h,
                                                  const int* __restrict__ src,
                                                  const int* __restrict__ rp,
                                                  unsigned short* __restrict__ mout, int nNodes) {
    const int node = blockIdx.x * 4 + (threadIdx.x >> 6);
    if (node >= nNodes) return;
    const int lane = threadIdx.x & 63;
    const size_t fo = (size_t)lane * 4;
    const int beg = __builtin_amdgcn_readfirstlane(rp[node]);
    const int end = __builtin_amdgcn_readfirstlane(rp[node + 1]);
    float a0 = 0.f, a1 = 0.f, a2 = 0.f, a3 = 0.f;
    int e = beg;
    for (; e + 4 <= end; e += 4) {
        const int s0 = src[e], s1 = src[e+1], s2 = src[e+2], s3 = src[e+3];
        ushort4 v0 = *(const ushort4*)&h[(size_t)s0 * 256 + fo];
        ushort4 v1 = *(const ushort4*)&h[(size_t)s1 * 256 + fo];
        ushort4 v2 = *(const ushort4*)&h[(size_t)s2 * 256 + fo];
        ushort4 v3 = *(const ushort4*)&h[(size_t)s3 * 256 + fo];
        a0 += bf2f(v0.x) + bf2f(v1.x) + bf2f(v2.x) + bf2f(v3.x);
        a1 += bf2f(v0.y) + bf2f(v1.y) + bf2f(v2.y) + bf2f(v3.y);
        a2 += bf2f(v0.z) + bf2f(v1.z) + bf2f(v2.z) + bf2f(v3.z);
        a3 += bf2f(v0.w) + bf2f(v1.w) + bf2f(v2.w) + bf2f(v3.w);
    }
    for (; e < end; ++e) {
        const int s = src[e];
        ushort4 v = *(const ushort4*)&h[(size_t)s * 256 + fo];
        a0 += bf2f(v.x); a1 += bf2f(v.y); a2 += bf2f(v.z); a3 += bf2f(v.w);
    }
    ushort4 o;
    o.x = f2bf(a0); o.y = f2bf(a1); o.z = f2bf(a2); o.w = f2bf(a3);
    *(ushort4*)&mout[(size_t)node * 256 + fo] = o;
}

// ---------------- MFMA GEMM, 2-phase double-buffered ----------------
// A0CVT: A0 is f32, reg-stage with cvt. A1F8: A1 is fp8, reg-stage with decode.
// OUTF8: emit fp8 only (skip bf16 store). Else emit bf16 only.
template <int NSEG, int EPMODE, bool OUTF8, bool A0CVT, bool A1F8>
__global__ __launch_bounds__(512) void gemm_kernel(
    const void* __restrict__ A0v, const void* __restrict__ A1v,
    const unsigned short* __restrict__ B0, const unsigned short* __restrict__ B1,
    const float* __restrict__ bias, unsigned short* __restrict__ Out,
    uint8_t* __restrict__ F8, int M) {
    __shared__ unsigned short Alds[2 * 128 * 32];
    __shared__ unsigned short Blds[2 * 256 * 32];
    __shared__ float ssq_lds[8][64];

    const int t = threadIdx.x;
    const int wid = t >> 6;
    const int lane = t & 63;
    const int wr = wid >> 1 >> 1 >> 0, wcDummy = 0; (void)wcDummy;
    const int wr2 = wid >> 2, wc = wid & 3;
    (void)wr;
    const int l15 = lane & 15;
    const int kh = lane >> 4;
    const int rowBase = blockIdx.x * 128;

    f4 acc[4][4];
#pragma unroll
    for (int m = 0; m < 4; m++)
#pragma unroll
        for (int n = 0; n < 4; n++) acc[m][n] = f4{0.f, 0.f, 0.f, 0.f};

    const int rA = t >> 2;
    const int sSlotA = (t & 3) ^ ((rA >> 1) & 3);
    int grA = rowBase + rA; if (grA > M - 1) grA = M - 1;
    const size_t gAoff = (size_t)grA * 256 + sSlotA * 8;
    const size_t gBoff0 = (size_t)rA * 256 + sSlotA * 8;
    const size_t gBoff1 = (size_t)(128 + rA) * 256 + sSlotA * 8;

    const int nsteps = NSEG * 8;
    auto STAGE = [&](int s, int buf) {
        const unsigned short* Bp = (NSEG == 2 && s >= 8) ? B1 : B0;
        const int k0 = (s & 7) * 32;
        const bool seg1 = (NSEG == 2 && s >= 8);
        if (!seg1) {
            if (A0CVT) {
                const float* Af = (const float*)A0v + gAoff + k0;
                const float4 v0 = *(const float4*)Af;
                const float4 v1 = *(const float4*)(Af + 4);
                bh8 o;
                o[0] = (short)f2bf(v0.x); o[1] = (short)f2bf(v0.y);
                o[2] = (short)f2bf(v0.z); o[3] = (short)f2bf(v0.w);
                o[4] = (short)f2bf(v1.x); o[5] = (short)f2bf(v1.y);
                o[6] = (short)f2bf(v1.z); o[7] = (short)f2bf(v1.w);
                *(bh8*)&Alds[buf * 4096 + wid * 512 + lane * 8] = o;
            } else {
                gload16((const unsigned short*)A0v + gAoff + k0, &Alds[buf * 4096 + wid * 512]);
            }
        } else {
            if (A1F8) {
                const uint8_t* Ab = (const uint8_t*)A1v;
                const uint2 p = *(const uint2*)&Ab[gAoff + k0];
                bh8 o;
                o[0] = (short)fp82bf(p.x & 0xffu);         o[1] = (short)fp82bf((p.x >> 8) & 0xffu);
                o[2] = (short)fp82bf((p.x >> 16) & 0xffu); o[3] = (short)fp82bf((p.x >> 24) & 0xffu);
                o[4] = (short)fp82bf(p.y & 0xffu);         o[5] = (short)fp82bf((p.y >> 8) & 0xffu);
                o[6] = (short)fp82bf((p.y >> 16) & 0xffu); o[7] = (short)fp82bf((p.y >> 24) & 0xffu);
                *(bh8*)&Alds[buf * 4096 + wid * 512 + lane * 8] = o;
            } else {
                gload16((const unsigned short*)A1v + gAoff + k0, &Alds[buf * 4096 + wid * 512]);
            }
        }
        gload16(Bp + gBoff0 + k0, &Blds[buf * 8192 + wid * 512]);
        gload16(Bp + gBoff1 + k0, &Blds[buf * 8192 + 4096 + wid * 512]);
    };

    STAGE(0, 0);
    asm volatile("s_waitcnt vmcnt(0)" ::: "memory");
    __syncthreads();

#pragma unroll 2
    for (int s = 0; s < nsteps; ++s) {
        const int cur = s & 1;
        if (s + 1 < nsteps) STAGE(s + 1, cur ^ 1);
        bh8 a[4], b[4];
#pragma unroll
        for (int m = 0; m < 4; m++) {
            const int ra = wr2 * 64 + m * 16 + l15;
            a[m] = *(const bh8*)&Alds[cur * 4096 + ra * 32 + ((kh ^ ((ra >> 1) & 3)) * 8)];
        }
#pragma unroll
        for (int n = 0; n < 4; n++) {
            const int rb = wc * 64 + n * 16 + l15;
            b[n] = *(const bh8*)&Blds[cur * 8192 + rb * 32 + ((kh ^ ((rb >> 1) & 3)) * 8)];
        }
#pragma unroll
        for (int m = 0; m < 4; m++)
#pragma unroll
            for (int n = 0; n < 4; n++)
                acc[m][n] = __builtin_amdgcn_mfma_f32_16x16x32_bf16(a[m], b[n], acc[m][n], 0, 0, 0);
        asm volatile("s_waitcnt vmcnt(0)" ::: "memory");
        __syncthreads();
    }

    const int cBase = wc * 64 + l15;
    float sq[4][4];
#pragma unroll
    for (int m = 0; m < 4; m++) { sq[m][0] = 0.f; sq[m][1] = 0.f; sq[m][2] = 0.f; sq[m][3] = 0.f; }
#pragma unroll
    for (int n = 0; n < 4; n++) {
        const float bv = bias[cBase + n * 16];
#pragma unroll
        for (int m = 0; m < 4; m++)
#pragma unroll
            for (int r = 0; r < 4; r++) {
                float v = acc[m][n][r] + bv;
                if (EPMODE != 1) v = fmaxf(v, 0.f);
                acc[m][n][r] = v;
                sq[m][r] += v * v;
            }
    }

    if (EPMODE != 2) {
#pragma unroll
        for (int mask = 1; mask < 16; mask <<= 1)
#pragma unroll
            for (int m = 0; m < 4; m++)
#pragma unroll
                for (int r = 0; r < 4; r++) sq[m][r] += __shfl_xor(sq[m][r], mask);
        if (l15 == 0) {
#pragma unroll
            for (int m = 0; m < 4; m++)
#pragma unroll
                for (int r = 0; r < 4; r++) ssq_lds[wid][m * 16 + kh * 4 + r] = sq[m][r];
        }
        __syncthreads();
#pragma unroll
        for (int m = 0; m < 4; m++)
#pragma unroll
            for (int r = 0; r < 4; r++) {
                const int rr = m * 16 + kh * 4 + r;
                const float s = ssq_lds[wr2 * 4 + 0][rr] + ssq_lds[wr2 * 4 + 1][rr] +
                                ssq_lds[wr2 * 4 + 2][rr] + ssq_lds[wr2 * 4 + 3][rr];
                sq[m][r] = 1.f / fmaxf(sqrtf(s), 1e-12f);
            }
    }

#pragma unroll
    for (int m = 0; m < 4; m++)
#pragma unroll
        for (int r = 0; r < 4; r++) {
            const int grow = rowBase + wr2 * 64 + m * 16 + kh * 4 + r;
            if (grow < M) {
#pragma unroll
                for (int n = 0; n < 4; n++) {
                    float v = acc[m][n][r];
                    if (EPMODE != 2) v *= sq[m][r];
                    if (EPMODE == 1) v = fmaxf(v, 0.f);
                    if (OUTF8) F8[(size_t)grow * 256 + cBase + n * 16] = f2fp8(v);
                    else       Out[(size_t)grow * 256 + cBase + n * 16] = f2bf(v);
                }
            }
        }
}

// ---------------- fused JK GEMM + post-classifier + log_softmax ----------------
// AF8: A (h2) is fp8, decode-staged. Phase 1: t = relu(h2 @ Wjk^T + bjk) -> Tlds.
// Phase 2: S reused for W_post bf16; logits MFMA + softmax.
template <bool AF8>
__global__ __launch_bounds__(256) void jkfinal_kernel(
    const void* __restrict__ Av,              // h2 fp8 [M][256] or bf16
    const unsigned short* __restrict__ Bjk,   // W_jk bf16 [256][256]
    const float* __restrict__ bjk,
    const float* __restrict__ Wp, const float* __restrict__ bp,
    float* __restrict__ out, int M) {
    __shared__ unsigned short S[20480];       // A dbuf 2x2048 | B dbuf 2x8192 ; reused as Wlds
    __shared__ unsigned short Tlds[64 * 256]; // swizzled t tile

    const int t = threadIdx.x;
    const int wid = t >> 6;
    const int lane = t & 63;
    const int wc = wid;
    const int l15 = lane & 15;
    const int kh = lane >> 4;
    const int rowBase = blockIdx.x * 64;

    f4 acc[4][4];
#pragma unroll
    for (int m = 0; m < 4; m++)
#pragma unroll
        for (int n = 0; n < 4; n++) acc[m][n] = f4{0.f, 0.f, 0.f, 0.f};

    const int rA = t >> 2;
    const int sSlotA = (t & 3) ^ ((rA >> 1) & 3);
    int grA = rowBase + rA; if (grA > M - 1) grA = M - 1;
    const size_t gAoff = (size_t)grA * 256 + sSlotA * 8;
    const size_t gBoff = (size_t)rA * 256 + sSlotA * 8;

    auto STAGE = [&](int s, int buf) {
        const int k0 = s * 32;
        if (AF8) {
            const uint8_t* Ab = (const uint8_t*)Av;
            const uint2 p = *(const uint2*)&Ab[gAoff + k0];
            bh8 o;
            o[0] = (short)fp82bf(p.x & 0xffu);         o[1] = (short)fp82bf((p.x >> 8) & 0xffu);
            o[2] = (short)fp82bf((p.x >> 16) & 0xffu); o[3] = (short)fp82bf((p.x >> 24) & 0xffu);
            o[4] = (short)fp82bf(p.y & 0xffu);         o[5] = (short)fp82bf((p.y >> 8) & 0xffu);
            o[6] = (short)fp82bf((p.y >> 16) & 0xffu); o[7] = (short)fp82bf((p.y >> 24) & 0xffu);
            *(bh8*)&S[buf * 2048 + wid * 512 + lane * 8] = o;
        } else {
            gload16((const unsigned short*)Av + gAoff + k0, &S[buf * 2048 + wid * 512]);
        }
#pragma unroll
        for (int p = 0; p < 4; ++p)
            gload16(Bjk + (size_t)p * 16384 + gBoff + k0,
                    &S[4096 + buf * 8192 + p * 2048 + wid * 512]);
    };

    STAGE(0, 0);
    asm volatile("s_waitcnt vmcnt(0)" ::: "memory");
    __syncthreads();

#pragma unroll 2
    for (int s = 0; s < 8; ++s) {
        const int cur = s & 1;
        if (s + 1 < 8) STAGE(s + 1, cur ^ 1);
        bh8 a[4], b[4];
#pragma unroll
        for (int m = 0; m < 4; m++) {
            const int ra = m * 16 + l15;
            a[m] = *(const bh8*)&S[cur * 2048 + ra * 32 + ((kh ^ ((ra >> 1) & 3)) * 8)];
        }
#pragma unroll
        for (int n = 0; n < 4; n++) {
            const int rb = wc * 64 + n * 16 + l15;
            b[n] = *(const bh8*)&S[4096 + cur * 8192 + rb * 32 + ((kh ^ ((rb >> 1) & 3)) * 8)];
        }
#pragma unroll
        for (int m = 0; m < 4; m++)
#pragma unroll
            for (int n = 0; n < 4; n++)
                acc[m][n] = __builtin_amdgcn_mfma_f32_16x16x32_bf16(a[m], b[n], acc[m][n], 0, 0, 0);
        asm volatile("s_waitcnt vmcnt(0)" ::: "memory");
        __syncthreads();
    }

    // phase-1 epilogue: relu(+bias) -> Tlds (swizzled)
    const int cBase = wc * 64 + l15;
#pragma unroll
    for (int n = 0; n < 4; n++) {
        const float bv = bjk[cBase + n * 16];
        const int slot = wc * 4 + n;
#pragma unroll
        for (int m = 0; m < 4; m++)
#pragma unroll
            for (int r = 0; r < 4; r++) {
                const int row = m * 16 + kh * 4 + r;
                const float v = fmaxf(acc[m][n][r] + bv, 0.f);
                Tlds[row * 256 + (((slot ^ ((row >> 2) & 7)) << 4) | l15)] = f2bf(v);
            }
    }
    // load W_post into S
    for (int i = t; i < 48 * 32; i += 256) {
        const int rb = i >> 5, slot = i & 31;
        bh8 o;
        if (rb < 47) {
#pragma unroll
            for (int j = 0; j < 8; j++) o[j] = (short)f2bf(Wp[rb * 256 + slot * 8 + j]);
        } else {
#pragma unroll
            for (int j = 0; j < 8; j++) o[j] = 0;
        }
        *(bh8*)&S[rb * 256 + ((slot ^ (rb & 7)) * 8)] = o;
    }
    __syncthreads();

    // phase 2: wave wid owns rows [wid*16, wid*16+16)
    const int lrow = wid * 16 + l15;
    bh8 a2[8];
#pragma unroll
    for (int ks = 0; ks < 8; ks++) {
        const int slot = ks * 2 + (kh >> 1);
        a2[ks] = *(const bh8*)&Tlds[lrow * 256 + (((slot ^ ((lrow >> 2) & 7)) << 4) | ((kh & 1) * 8))];
    }
    f4 acc2[3];
#pragma unroll
    for (int n = 0; n < 3; n++) acc2[n] = f4{0.f, 0.f, 0.f, 0.f};
#pragma unroll
    for (int ks = 0; ks < 8; ks++)
#pragma unroll
        for (int n = 0; n < 3; n++) {
            const int rb = n * 16 + l15;
            const bh8 b = *(const bh8*)&S[rb * 256 + (((ks * 4 + kh) ^ (rb & 7)) * 8)];
            acc2[n] = __builtin_amdgcn_mfma_f32_16x16x32_bf16(a2[ks], b, acc2[n], 0, 0, 0);
        }

    const int c0 = l15, c1 = 16 + l15, c2 = 32 + l15;
    const float b0 = bp[c0], b1 = bp[c1];
    const float b2 = (l15 < 15) ? bp[c2] : 0.f;
#pragma unroll
    for (int r = 0; r < 4; r++) {
        const int grow = rowBase + wid * 16 + kh * 4 + r;
        const float x0 = acc2[0][r] + b0;
        const float x1 = acc2[1][r] + b1;
        const float x2 = (l15 < 15) ? (acc2[2][r] + b2) : -3.0e38f;
        float mx = fmaxf(fmaxf(x0, x1), x2);
#pragma unroll
        for (int msk = 1; msk < 16; msk <<= 1) mx = fmaxf(mx, __shfl_xor(mx, msk));
        float se = __expf(x0 - mx) + __expf(x1 - mx) + ((l15 < 15) ? __expf(x2 - mx) : 0.f);
#pragma unroll
        for (int msk = 1; msk < 16; msk <<= 1) se += __shfl_xor(se, msk);
        const float ls = __logf(se) + mx;
        if (grow < M) {
            float* orow = &out[(size_t)grow * 47];
            orow[c0] = x0 - ls;
            orow[c1] = x1 - ls;
            if (l15 < 15) orow[c2] = x2 - ls;
        }
    }
}

extern "C" void kernel_launch(void* const* d_in, const int* in_sizes, int n_in,
                              void* d_out, int out_size, void* d_ws, size_t ws_size,
                              hipStream_t stream) {
    const float* x      = (const float*)d_in[0];
    const int*   src    = (const int*)d_in[1];
    const int*   dst    = (const int*)d_in[2];
    const float* W_pre  = (const float*)d_in[3];
    const float* b_pre  = (const float*)d_in[4];
    const float* Wl1    = (const float*)d_in[5];
    const float* bl1    = (const float*)d_in[6];
    const float* Wr1    = (const float*)d_in[7];
    const float* Wl2    = (const float*)d_in[8];
    const float* bl2    = (const float*)d_in[9];
    const float* Wr2    = (const float*)d_in[10];
    const float* W_jk   = (const float*)d_in[11];
    const float* b_jk   = (const float*)d_in[12];
    const float* W_post = (const float*)d_in[13];
    const float* b_post = (const float*)d_in[14];

    const int N = in_sizes[0] / 256;
    const int E = in_sizes[1];

    char* ws = (char*)d_ws;
    char* ws0 = ws;
    const size_t HB = (size_t)N * 256 * 2;
    unsigned short* bufA = (unsigned short*)ws; ws += HB;   // fallback h2
    unsigned short* bufB = (unsigned short*)ws; ws += HB;   // fallback h0
    unsigned short* bufC = (unsigned short*)ws; ws += HB;   // m1 -> m2
    unsigned short* bufD = (unsigned short*)ws; ws += HB;   // fallback h1
    unsigned short* wbBase = (unsigned short*)ws; ws += (size_t)6 * 65536 * 2;
    int* rp = (int*)ws; ws += (size_t)(N + 1) * 4;
    uint8_t* f8A = (uint8_t*)ws; ws += (size_t)N * 256;     // h0 -> h2
    uint8_t* f8B = (uint8_t*)ws; ws += (size_t)N * 256;     // h1
    const bool useFp8 = ((size_t)(ws - ws0) <= ws_size);

    const int nbr = (N + 1 + 255) / 256;
    prep_kernel<<<384 + nbr, 256, 0, stream>>>(W_pre, Wl1, Wr1, Wl2, Wr2, W_jk,
                                               wbBase, dst, rp, N, E);
    unsigned short* wb[6];
    for (int i = 0; i < 6; i++) wb[i] = wbBase + (size_t)i * 65536;

    const int gB = (N + 127) / 128;
    const int gAgg = (N + 3) / 4;
    if (useFp8) {
        gemm_kernel<1, 0, true, true, false><<<gB, 512, 0, stream>>>(x, nullptr, wb[0], nullptr, b_pre, nullptr, f8A, N);
        agg_fp8_kernel<<<gAgg, 256, 0, stream>>>((const uint32_t*)f8A, src, rp, bufC, N);
        gemm_kernel<2, 1, true, false, true><<<gB, 512, 0, stream>>>(bufC, f8A, wb[1], wb[2], bl1, nullptr, f8B, N);
        agg_fp8_kernel<<<gAgg, 256, 0, stream>>>((const uint32_t*)f8B, src, rp, bufC, N);
        gemm_kernel<2, 1, true, false, true><<<gB, 512, 0, stream>>>(bufC, f8B, wb[3], wb[4], bl2, nullptr, f8A, N);
        jkfinal_kernel<true><<<(N + 63) / 64, 256, 0, stream>>>(f8A, wb[5], b_jk, W_post, b_post,
                                                                (float*)d_out, N);
    } else {
        gemm_kernel<1, 0, false, true, false><<<gB, 512, 0, stream>>>(x, nullptr, wb[0], nullptr, b_pre, bufB, nullptr, N);
        agg_kernel<<<gAgg, 256, 0, stream>>>(bufB, src, rp, bufC, N);
        gemm_kernel<2, 1, false, false, false><<<gB, 512, 0, stream>>>(bufC, bufB, wb[1], wb[2], bl1, bufD, nullptr, N);
        agg_kernel<<<gAgg, 256, 0, stream>>>(bufD, src, rp, bufC, N);
        gemm_kernel<2, 1, false, false, false><<<gB, 512, 0, stream>>>(bufC, bufD, wb[3], wb[4], bl2, bufA, nullptr, N);
        jkfinal_kernel<false><<<(N + 63) / 64, 256, 0, stream>>>(bufA, wb[5], b_jk, W_post, b_post,
                                                                 (float*)d_out, N);
    }
}